// Round 8
// baseline (9251.434 us; speedup 1.0000x reference)
//
#include <hip/hip_runtime.h>
#include <cstdint>

// Reference model (evidence through R7):
//  - selection (FPS argmax/min chain) runs on RAW f32 coords;
//  - ref Output-0 coords are bf16-grid values (R0: 4.65625, R3: 3.609375 both
//    exactly on the bf16 grid) -> we write bf16-RNE-rounded coords (safe
//    either way: <=0.018 error if ref is raw);
//  - plain-L2R f32 and f64 selections are bitwise-eliminated (R3=R4 yet both
//    off by a few flips) -> ref op order differs: XLA/LLVM FMA contraction.
//    V1 fusion (DAGCombiner: fuse first fmul of each fadd):
//      d = fma(dz,dz, fma(dx,dx, r(dy*dy))), dx/dy/dz = plain f32 subs.
#pragma clang fp contract(off)

#define B_ 16
#define N_ 16384
#define K_ 4096
#define THREADS_ 512
#define PTS_ (N_ / THREADS_)   // 32 points per thread
#define NW_ (THREADS_ / 64)    // 8 waves per block

// f32 -> bf16 RNE, returned as the bf16-representable f32 (finite inputs)
__device__ __forceinline__ float bfr(float f) {
  union { float f; uint32_t i; } c; c.f = f;
  c.i = (c.i + 0x7FFFu + ((c.i >> 16) & 1u)) & 0xFFFF0000u;
  return c.f;
}

// FMA-V1 squared distance on raw f32 coords
__device__ __forceinline__ float dist_v1(float px, float py, float pz,
                                         float cx, float cy, float cz) {
  const float dx = px - cx;
  const float dy = py - cy;
  const float dz = pz - cz;
  return __builtin_fmaf(dz, dz, __builtin_fmaf(dx, dx, dy * dy));
}

__global__ __launch_bounds__(THREADS_, 2) void fps_kernel(
    const float* __restrict__ x, float* __restrict__ out)
{
#pragma clang fp contract(off)
  const int b    = blockIdx.x;
  const int t    = threadIdx.x;
  const int lane = t & 63;
  const int wave = t >> 6;

  // parity-double-buffered per-wave argmax slots: one barrier per iteration
  __shared__ float s_v[2][NW_];
  __shared__ int   s_g[2][NW_];

  const float* xb  = x + (size_t)b * (N_ * 3);
  float* out_x     = out;                        // [B*K*3] f32 (bf16-grid values)
  float* out_batch = out + (size_t)B_ * K_ * 3;  // [B*K]   f32 cloud ids

  // batch output (buffer re-poisoned every call -> rewrite every call)
  {
    const float bb = (float)b;
    for (int i = t; i < K_; i += THREADS_) out_batch[b * K_ + i] = bb;
  }

  // Load this thread's 32 points, raw f32 (strided: g = s*512 + t)
  float px[PTS_], py[PTS_], pz[PTS_], mind[PTS_];
#pragma unroll
  for (int s = 0; s < PTS_; ++s) {
    const int g = s * THREADS_ + t;
    px[s] = xb[3 * g + 0];
    py[s] = xb[3 * g + 1];
    pz[s] = xb[3 * g + 2];
  }

  // ---- iteration 0: seed = point 0 ----
  float cx = xb[0], cy = xb[1], cz = xb[2];
  if (t == 0) {
    const uint64_t o = ((uint64_t)b * K_) * 3;
    out_x[o + 0] = bfr(cx); out_x[o + 1] = bfr(cy); out_x[o + 2] = bfr(cz);
  }

  float bv = -1.0f; int bg = 0;
#pragma unroll
  for (int s = 0; s < PTS_; ++s) {
    const float d = dist_v1(px[s], py[s], pz[s], cx, cy, cz);
    mind[s] = d;
    const int g = s * THREADS_ + t;
    if (d > bv) { bv = d; bg = g; }   // strict > + ascending g: first-index tie-break
  }
  // wave-level (value, first-index) argmax reduction
#pragma unroll
  for (int m = 32; m >= 1; m >>= 1) {
    const float ov = __shfl_xor(bv, m, 64);
    const int   og = __shfl_xor(bg, m, 64);
    if (ov > bv || (ov == bv && og < bg)) { bv = ov; bg = og; }
  }
  if (lane == 0) { s_v[0][wave] = bv; s_g[0][wave] = bg; }
  __syncthreads();

  // ---- iterations 1..K-1 ----
  for (int j = 1; j < K_; ++j) {
    const int rp = (j - 1) & 1;
    const int wp = j & 1;

    // finalize block argmax of previous round (all threads redundantly)
    float v = s_v[rp][0]; int g = s_g[rp][0];
#pragma unroll
    for (int w = 1; w < NW_; ++w) {
      const float ov = s_v[rp][w]; const int og = s_g[rp][w];
      if (ov > v || (ov == v && og < g)) { v = ov; g = og; }
    }

    // broadcast chosen point's raw coords
    cx = xb[3 * g + 0];
    cy = xb[3 * g + 1];
    cz = xb[3 * g + 2];
    if (t == 0) {
      const uint64_t o = ((uint64_t)b * K_ + j) * 3;
      out_x[o + 0] = bfr(cx); out_x[o + 1] = bfr(cy); out_x[o + 2] = bfr(cz);
    }

    // update mind + fused local argmax scan for next round
    bv = -1.0f; bg = 0;
#pragma unroll
    for (int s = 0; s < PTS_; ++s) {
      const float d  = dist_v1(px[s], py[s], pz[s], cx, cy, cz);
      const float m2 = fminf(mind[s], d);
      mind[s] = m2;
      const int gg = s * THREADS_ + t;
      if (m2 > bv) { bv = m2; bg = gg; }
    }
#pragma unroll
    for (int m = 32; m >= 1; m >>= 1) {
      const float ov = __shfl_xor(bv, m, 64);
      const int   og = __shfl_xor(bg, m, 64);
      if (ov > bv || (ov == bv && og < bg)) { bv = ov; bg = og; }
    }
    if (lane == 0) { s_v[wp][wave] = bv; s_g[wp][wave] = bg; }
    __syncthreads();
  }
}

extern "C" void kernel_launch(void* const* d_in, const int* in_sizes, int n_in,
                              void* d_out, int out_size, void* d_ws, size_t ws_size,
                              hipStream_t stream) {
  const float* x = (const float*)d_in[0];  // f32, [B*N, 3]
  float* out     = (float*)d_out;          // f32: [B*K*3] coords + [B*K] batch
  (void)in_sizes; (void)n_in; (void)out_size; (void)d_ws; (void)ws_size;
  hipLaunchKernelGGL(fps_kernel, dim3(B_), dim3(THREADS_), 0, stream, x, out);
}